// Round 11
// baseline (296.759 us; speedup 1.0000x reference)
//
#include <hip/hip_runtime.h>
#include <hip/hip_bf16.h>
#include <hip/hip_cooperative_groups.h>

namespace cg = cooperative_groups;

#define N_NODES 100000
#define N_EDGES 1600000
#define DIM 64
#define NB1 391                  // ceil(N_NODES/256)
#define NGROUPS (N_NODES / 4)    // 25000
#define NBLK 1024                // 4 blocks/CU co-resident (coop launch)
#define NCLASS_BLK (NBLK / 8)    // 128 blocks per XCD class
#define GSZ (NBLK * 256)
#define CSTRIDE 100096           // per-copy counts stride (ints)
#define E4 (N_EDGES / 4)         // 400000
#define E4BLK 1563
#define ND4 (N_NODES * DIM / 4)  // 1600000
#define NBLK_GM 1536             // fallback gather grid
#define SLICE_INTS 400000        // y16 slice: 100000 nodes * 16 B

// ---------------- workspace layout (int units) ----------------
#define OFF_COUNTS8 0            // 8 * CSTRIDE = 800768
#define OFF_SOUT    800768       // 80 (65 floats used)
#define OFF_TOT     800848
#define OFF_OFFSETS 900944
#define OFF_BSUMS   1000960
#define OFF_CSR     1001472      // 1600000
#define OFF_RANK8   2601472      // 400000
#define OFF_Y16     3001472      // 3200000: mega = 8 slices of 400000; fallback = node-major

__device__ __forceinline__ float blo(unsigned u) { return __uint_as_float(u << 16); }
__device__ __forceinline__ float bhi(unsigned u) { return __uint_as_float(u & 0xffff0000u); }
__device__ __forceinline__ unsigned packbf2(float a, float b) {
    __hip_bfloat162 p = __float22bfloat162_rn(make_float2(a, b));
    return *reinterpret_cast<unsigned*>(&p);
}

// ===========================================================================
// Cooperative mega-kernel: 8 phases with grid.sync() boundaries
//  P0 zero | P1 class-aligned sliced convert + XCD-private hist |
//  P2 copy-prefix+blocksums | P3 offsets | P4 fill CSR |
//  P5a column-sliced gather -> bf16 agg rows (in dead edge buffer) |
//  P5b stream agg + MLP + weighted reduce | P6 finalize
// ===========================================================================
__global__ __launch_bounds__(256, 4) void mega_kernel(
    const float* __restrict__ x,
    int* ebuf,                       // edge_index buffer: src | dst ; reused as agg after P4
    const float* __restrict__ weights,
    const float* __restrict__ W1,
    const float* __restrict__ b1,
    const float* __restrict__ W2,
    const float* __restrict__ b2,
    int* __restrict__ ws,
    float* __restrict__ out)
{
    cg::grid_group grid = cg::this_grid();

    __shared__ float W1s[DIM * DIM];      // 16 KB
    __shared__ float vbuf[4][4][DIM];     // 4 KB
    __shared__ float sred[4][DIM];        // 1 KB
    __shared__ int   sscan[256];          // 1 KB
    __shared__ int   base_sh;

    int*      counts8 = ws + OFF_COUNTS8;
    float*    sout    = (float*)(ws + OFF_SOUT);
    int*      tot     = ws + OFF_TOT;
    int*      offsets = ws + OFF_OFFSETS;
    int*      bsums   = ws + OFF_BSUMS;
    int*      csr     = ws + OFF_CSR;
    unsigned* rank8   = (unsigned*)(ws + OFF_RANK8);
    unsigned* ysl     = (unsigned*)(ws + OFF_Y16);

    const int* src = ebuf;
    const int* dst = ebuf + N_EDGES;
    unsigned*  aggu = (unsigned*)ebuf;    // after P4: bf16 agg rows, 32 uints/node

    const int tid  = threadIdx.x;
    const int bid  = blockIdx.x;
    const int gtid = bid * 256 + tid;
    const int cls  = bid & 7;             // XCD class (round-robin heuristic)
    const int rb   = bid >> 3;

    // ---- P0: zero counts8 (+sout) ----
    for (int i = gtid; i < OFF_SOUT + 80; i += GSZ) ws[i] = 0;
    grid.sync();

    // ---- P1: class-aligned octet-sliced convert + XCD-private hist ----
    {
        const float4* x4 = (const float4*)x;
        uint2* slice2 = (uint2*)(ysl + cls * SLICE_INTS);   // 2 uint2 per node
        for (int t = rb * 256 + tid; t < N_NODES * 2; t += NCLASS_BLK * 256) {
            int node = t >> 1, h2 = t & 1;
            float4 v = x4[node * 16 + cls * 2 + h2];
            uint2 o;
            o.x = packbf2(v.x, v.y);
            o.y = packbf2(v.z, v.w);
            slice2[node * 2 + h2] = o;
        }
    }
    for (int i = gtid; i < E4; i += GSZ) {
        int4 d = ((const int4*)dst)[i];
        int* cnt = counts8 + (((unsigned)i >> 8) & 7) * CSTRIDE;
        unsigned r0 = (unsigned)atomicAdd(&cnt[d.x], 1);
        unsigned r1 = (unsigned)atomicAdd(&cnt[d.y], 1);
        unsigned r2 = (unsigned)atomicAdd(&cnt[d.z], 1);
        unsigned r3 = (unsigned)atomicAdd(&cnt[d.w], 1);
        rank8[i] = r0 | (r1 << 8) | (r2 << 16) | (r3 << 24);
    }
    grid.sync();

    // ---- P2: per-node 8-copy exclusive prefix + total + block sums ----
    if (bid < NB1) {
        int idx = bid * 256 + tid;
        int run = 0;
        if (idx < N_NODES) {
            #pragma unroll
            for (int k = 0; k < 8; ++k) {
                int v = counts8[k * CSTRIDE + idx];
                counts8[k * CSTRIDE + idx] = run;
                run += v;
            }
            tot[idx] = run;
        }
        sscan[tid] = (idx < N_NODES) ? run : 0;
        __syncthreads();
        for (int d = 128; d > 0; d >>= 1) {
            if (tid < d) sscan[tid] += sscan[tid + d];
            __syncthreads();
        }
        if (tid == 0) bsums[bid] = sscan[0];
    }
    grid.sync();

    // ---- P3: offsets + fold base into counts8 ----
    if (bid < NB1) {
        int contrib = 0;
        if (tid < bid) contrib += bsums[tid];
        if (tid + 256 < bid) contrib += bsums[tid + 256];
        sscan[tid] = contrib;
        __syncthreads();
        for (int d = 128; d > 0; d >>= 1) {
            if (tid < d) sscan[tid] += sscan[tid + d];
            __syncthreads();
        }
        if (tid == 0) base_sh = sscan[0];
        __syncthreads();
        const int base = base_sh;
        __syncthreads();

        int idx = bid * 256 + tid;
        int c = (idx < N_NODES) ? tot[idx] : 0;
        sscan[tid] = c;
        __syncthreads();
        for (int d = 1; d < 256; d <<= 1) {
            int add = (tid >= d) ? sscan[tid - d] : 0;
            __syncthreads();
            sscan[tid] += add;
            __syncthreads();
        }
        int excl = (tid == 0) ? 0 : sscan[tid - 1];
        int off = base + excl;
        if (idx < N_NODES) {
            offsets[idx] = off;
            #pragma unroll
            for (int k = 0; k < 8; ++k)
                counts8[k * CSTRIDE + idx] += off;
        }
        if (idx == 0) offsets[N_NODES] = N_EDGES;
    }
    grid.sync();

    // ---- P4: fill CSR (zero atomics) ----
    for (int e4 = gtid; e4 < E4; e4 += GSZ) {
        int4 s = ((const int4*)src)[e4];
        int4 d = ((const int4*)dst)[e4];
        unsigned rp = rank8[e4];
        const int* base = counts8 + (((unsigned)e4 >> 8) & 7) * CSTRIDE;
        csr[base[d.x] + (int)(rp & 255u)]         = s.x;
        csr[base[d.y] + (int)((rp >> 8) & 255u)]  = s.y;
        csr[base[d.z] + (int)((rp >> 16) & 255u)] = s.z;
        csr[base[d.w] + (int)((rp >> 24) & 255u)] = s.w;
    }
    grid.sync();
    // ebuf's src/dst are now dead; it becomes the agg row buffer.

    // ---- P5a: column-sliced gather. Class c reads ONLY slice c (1.6 MB,
    //      per-XCD L2-resident). 16-lane group per node; loop over degree.
    {
        const uint4* sl = (const uint4*)(ysl + cls * SLICE_INTS);
        const int lane = tid & 63;
        const int wave = tid >> 6;
        const int n = lane >> 4;          // node within group
        const int e = lane & 15;          // edge slot within 16
        const int oidx = (lane < 5 ? lane : 4);

        for (int g = rb * 4 + wave; g < NGROUPS; g += NCLASS_BLK * 4) {
            const int i0 = g * 4;
            int off_l = offsets[i0 + oidx];
            int bg0 = __builtin_amdgcn_readfirstlane(__shfl(off_l, 0));
            int bg1 = __builtin_amdgcn_readfirstlane(__shfl(off_l, 1));
            int bg2 = __builtin_amdgcn_readfirstlane(__shfl(off_l, 2));
            int bg3 = __builtin_amdgcn_readfirstlane(__shfl(off_l, 3));
            int en  = __builtin_amdgcn_readfirstlane(__shfl(off_l, 4));
            int dd0 = bg1 - bg0, dd1 = bg2 - bg1, dd2 = bg3 - bg2, dd3 = en - bg3;
            int maxdd = max(max(dd0, dd1), max(dd2, dd3));
            int tmax = (maxdd + 15) >> 4;

            int mybg = (n < 2) ? (n == 0 ? bg0 : bg1) : (n == 2 ? bg2 : bg3);
            int mydd = (n < 2) ? (n == 0 ? dd0 : dd1) : (n == 2 ? dd2 : dd3);

            float a0 = 0.f, a1 = 0.f, a2 = 0.f, a3 = 0.f;
            float a4 = 0.f, a5 = 0.f, a6 = 0.f, a7 = 0.f;
            for (int t = 0; t < tmax; ++t) {
                int j = t * 16 + e;
                bool valid = j < mydd;
                int jj = valid ? (mybg + j) : 0;     // clamp: no OOB csr read
                int idx = csr[jj];                   // in [0, N_NODES)
                uint4 rr = sl[idx];                  // 16 B, L2-resident slice
                float m = valid ? 1.f : 0.f;
                a0 = fmaf(m, blo(rr.x), a0); a1 = fmaf(m, bhi(rr.x), a1);
                a2 = fmaf(m, blo(rr.y), a2); a3 = fmaf(m, bhi(rr.y), a3);
                a4 = fmaf(m, blo(rr.z), a4); a5 = fmaf(m, bhi(rr.z), a5);
                a6 = fmaf(m, blo(rr.w), a6); a7 = fmaf(m, bhi(rr.w), a7);
            }
            // butterfly within each 16-lane group
            #pragma unroll
            for (int m = 1; m <= 8; m <<= 1) {
                a0 += __shfl_xor(a0, m); a1 += __shfl_xor(a1, m);
                a2 += __shfl_xor(a2, m); a3 += __shfl_xor(a3, m);
                a4 += __shfl_xor(a4, m); a5 += __shfl_xor(a5, m);
                a6 += __shfl_xor(a6, m); a7 += __shfl_xor(a7, m);
            }
            if (e < 4) {
                float lo = (e == 0) ? a0 : (e == 1) ? a2 : (e == 2) ? a4 : a6;
                float hi = (e == 0) ? a1 : (e == 1) ? a3 : (e == 2) ? a5 : a7;
                aggu[(i0 + n) * 32 + cls * 4 + e] = packbf2(lo, hi);
            }
        }
    }
    grid.sync();

    // ---- P5b: stream agg rows + self term + MLP + weighted reduce ----
    {
        const int lane = tid & 63;
        const int wave = tid >> 6;

        for (int i = tid; i < DIM * DIM; i += 256) W1s[i] = W1[i];
        __syncthreads();

        const float bias = b1[lane];
        float sacc  = 0.f;
        float swacc = 0.f;

        for (int g = bid * 4 + wave; g < NGROUPS; g += NBLK * 4) {
            const int i0 = g * 4;
            #pragma unroll
            for (int n = 0; n < 4; ++n) {
                unsigned u = aggu[(i0 + n) * 32 + (lane >> 1)];   // coalesced 128B/row
                float v = (lane & 1) ? bhi(u) : blo(u);
                v += x[(size_t)(i0 + n) * DIM + lane];            // fp32 self term
                vbuf[wave][n][lane] = v;
            }

            float a0 = bias, a1 = bias, a2 = bias, a3 = bias;
            #pragma unroll
            for (int k = 0; k < DIM; k += 4) {
                float4 q0 = *(const float4*)&vbuf[wave][0][k];
                float4 q1 = *(const float4*)&vbuf[wave][1][k];
                float4 q2 = *(const float4*)&vbuf[wave][2][k];
                float4 q3 = *(const float4*)&vbuf[wave][3][k];
                float w0 = W1s[(k + 0) * DIM + lane];
                float w1 = W1s[(k + 1) * DIM + lane];
                float w2 = W1s[(k + 2) * DIM + lane];
                float w3 = W1s[(k + 3) * DIM + lane];
                a0 = fmaf(q0.x, w0, a0); a0 = fmaf(q0.y, w1, a0);
                a0 = fmaf(q0.z, w2, a0); a0 = fmaf(q0.w, w3, a0);
                a1 = fmaf(q1.x, w0, a1); a1 = fmaf(q1.y, w1, a1);
                a1 = fmaf(q1.z, w2, a1); a1 = fmaf(q1.w, w3, a1);
                a2 = fmaf(q2.x, w0, a2); a2 = fmaf(q2.y, w1, a2);
                a2 = fmaf(q2.z, w2, a2); a2 = fmaf(q2.w, w3, a2);
                a3 = fmaf(q3.x, w0, a3); a3 = fmaf(q3.y, w1, a3);
                a3 = fmaf(q3.z, w2, a3); a3 = fmaf(q3.w, w3, a3);
            }

            const float wt0 = weights[i0 + 0];
            const float wt1 = weights[i0 + 1];
            const float wt2 = weights[i0 + 2];
            const float wt3 = weights[i0 + 3];
            sacc = fmaf(fmaxf(a0, 0.f), wt0, sacc);
            sacc = fmaf(fmaxf(a1, 0.f), wt1, sacc);
            sacc = fmaf(fmaxf(a2, 0.f), wt2, sacc);
            sacc = fmaf(fmaxf(a3, 0.f), wt3, sacc);
            if (lane == 0) swacc += wt0 + wt1 + wt2 + wt3;
        }

        sred[wave][lane] = sacc;
        __syncthreads();
        if (wave == 0) {
            float t = sred[0][lane] + sred[1][lane] + sred[2][lane] + sred[3][lane];
            atomicAdd(&sout[lane], t);
        }
        if (lane == 0) atomicAdd(&sout[DIM], swacc);
    }
    grid.sync();

    // ---- P6: finalize (block 0): out = s @ W2 + sw * b2 ----
    if (bid == 0 && tid < DIM) {
        const int j = tid;
        const float sw = sout[DIM];
        float acc = sw * b2[j];
        #pragma unroll
        for (int k = 0; k < DIM; ++k)
            acc = fmaf(sout[k], W2[k * DIM + j], acc);
        out[j] = acc;
    }
}

// ===========================================================================
// Fallback multi-kernel path (proven R8 structure, node-major y16)
// ===========================================================================
__global__ __launch_bounds__(256) void convert_hist_kernel(
    const float* __restrict__ x, unsigned* __restrict__ y,
    const int* __restrict__ dst, int* __restrict__ counts8,
    unsigned* __restrict__ rank8)
{
    int i = blockIdx.x * 256 + threadIdx.x;
    if (i < ND4) {
        float4 v = ((const float4*)x)[i];
        uint2 o;
        o.x = packbf2(v.x, v.y);
        o.y = packbf2(v.z, v.w);
        ((uint2*)y)[i] = o;
    }
    if (i < E4) {
        int4 d = ((const int4*)dst)[i];
        int* cnt = counts8 + (((unsigned)i >> 8) & 7) * CSTRIDE;
        unsigned r0 = (unsigned)atomicAdd(&cnt[d.x], 1);
        unsigned r1 = (unsigned)atomicAdd(&cnt[d.y], 1);
        unsigned r2 = (unsigned)atomicAdd(&cnt[d.z], 1);
        unsigned r3 = (unsigned)atomicAdd(&cnt[d.w], 1);
        rank8[i] = r0 | (r1 << 8) | (r2 << 16) | (r3 << 24);
    }
}

__global__ __launch_bounds__(256) void colsum_blocksum_kernel(
    int* __restrict__ counts8, int* __restrict__ tot, int* __restrict__ bsums)
{
    __shared__ int s[256];
    int t = threadIdx.x;
    int idx = blockIdx.x * 256 + t;
    int run = 0;
    if (idx < N_NODES) {
        #pragma unroll
        for (int k = 0; k < 8; ++k) {
            int v = counts8[k * CSTRIDE + idx];
            counts8[k * CSTRIDE + idx] = run;
            run += v;
        }
        tot[idx] = run;
    }
    s[t] = (idx < N_NODES) ? run : 0;
    __syncthreads();
    for (int d = 128; d > 0; d >>= 1) {
        if (t < d) s[t] += s[t + d];
        __syncthreads();
    }
    if (t == 0) bsums[blockIdx.x] = s[0];
}

__global__ __launch_bounds__(256) void offsets_kernel(
    const int* __restrict__ tot, const int* __restrict__ bsums,
    int* __restrict__ offsets, int* __restrict__ counts8)
{
    __shared__ int s[256];
    __shared__ int base_sh;
    const int t = threadIdx.x;
    const int bid = blockIdx.x;

    int contrib = 0;
    if (t < bid) contrib += bsums[t];
    if (t + 256 < bid) contrib += bsums[t + 256];
    s[t] = contrib;
    __syncthreads();
    for (int d = 128; d > 0; d >>= 1) {
        if (t < d) s[t] += s[t + d];
        __syncthreads();
    }
    if (t == 0) base_sh = s[0];
    __syncthreads();
    const int base = base_sh;
    __syncthreads();

    int idx = bid * 256 + t;
    int c = (idx < N_NODES) ? tot[idx] : 0;
    s[t] = c;
    __syncthreads();
    for (int d = 1; d < 256; d <<= 1) {
        int add = (t >= d) ? s[t - d] : 0;
        __syncthreads();
        s[t] += add;
        __syncthreads();
    }
    int excl = (t == 0) ? 0 : s[t - 1];
    int off = base + excl;
    if (idx < N_NODES) {
        offsets[idx] = off;
        #pragma unroll
        for (int k = 0; k < 8; ++k)
            counts8[k * CSTRIDE + idx] += off;
    }
    if (idx == 0) offsets[N_NODES] = N_EDGES;
}

__global__ __launch_bounds__(256) void fill_kernel(
    const int* __restrict__ src, const int* __restrict__ dst,
    const int* __restrict__ counts8, const unsigned* __restrict__ rank8,
    int* __restrict__ csr)
{
    int e4 = blockIdx.x * 256 + threadIdx.x;
    if (e4 < E4) {
        int4 s = ((const int4*)src)[e4];
        int4 d = ((const int4*)dst)[e4];
        unsigned rp = rank8[e4];
        const int* base = counts8 + (((unsigned)e4 >> 8) & 7) * CSTRIDE;
        csr[base[d.x] + (int)(rp & 255u)]         = s.x;
        csr[base[d.y] + (int)((rp >> 8) & 255u)]  = s.y;
        csr[base[d.z] + (int)((rp >> 16) & 255u)] = s.z;
        csr[base[d.w] + (int)((rp >> 24) & 255u)] = s.w;
    }
}

__global__ __launch_bounds__(256) void gather_mlp_kernel(
    const float* __restrict__ x, const unsigned* __restrict__ y16,
    const int* __restrict__ offsets, const int* __restrict__ csr,
    const float* __restrict__ weights, const float* __restrict__ W1,
    const float* __restrict__ b1, float* __restrict__ sout)
{
    __shared__ float W1s[DIM * DIM];
    __shared__ float vbuf[4][4][DIM];
    __shared__ float sred[4][DIM];

    const int tid  = threadIdx.x;
    const int lane = tid & 63;
    const int wave = tid >> 6;
    const int slot = lane >> 3;
    const int h    = lane & 7;

    for (int i = tid; i < DIM * DIM; i += 256) W1s[i] = W1[i];
    __syncthreads();

    const float bias = b1[lane];
    float sacc  = 0.f;
    float swacc = 0.f;

    const uint4* yrows = (const uint4*)y16;

    for (int g = blockIdx.x * 4 + wave; g < NGROUPS; g += NBLK_GM * 4) {
        const int i0 = g * 4;

        int off_l = offsets[i0 + (lane < 5 ? lane : 4)];
        int bg[4], dd[4];
        #pragma unroll
        for (int n = 0; n < 4; ++n) {
            int b = __builtin_amdgcn_readfirstlane(__shfl(off_l, n));
            int e = __builtin_amdgcn_readfirstlane(__shfl(off_l, n + 1));
            bg[n] = b; dd[n] = e - b;
        }

        int idxv[4];
        float selfv[4];
        #pragma unroll
        for (int n = 0; n < 4; ++n)
            idxv[n] = (lane < dd[n]) ? csr[bg[n] + lane] : 0;
        #pragma unroll
        for (int n = 0; n < 4; ++n)
            selfv[n] = x[(size_t)(i0 + n) * DIM + lane];

        uint4 r[4][3];
        #pragma unroll
        for (int n = 0; n < 4; ++n) {
            #pragma unroll
            for (int c = 0; c < 3; ++c) {
                r[n][c] = make_uint4(0u, 0u, 0u, 0u);
                if (c * 8 < dd[n]) {
                    const int e = c * 8 + slot;
                    const int s = __shfl(idxv[n], e);
                    uint4 rr = yrows[(size_t)s * 8 + h];
                    if (e < dd[n]) r[n][c] = rr;
                }
            }
        }

        #pragma unroll
        for (int n = 0; n < 4; ++n) {
            float a0 = 0.f, a1 = 0.f, a2 = 0.f, a3 = 0.f;
            float a4 = 0.f, a5 = 0.f, a6 = 0.f, a7 = 0.f;
            #pragma unroll
            for (int c = 0; c < 3; ++c) {
                if (c * 8 < dd[n]) {
                    uint4 rr = r[n][c];
                    a0 += blo(rr.x); a1 += bhi(rr.x);
                    a2 += blo(rr.y); a3 += bhi(rr.y);
                    a4 += blo(rr.z); a5 += bhi(rr.z);
                    a6 += blo(rr.w); a7 += bhi(rr.w);
                }
            }
            if (dd[n] > 24) {
                const int dcap = dd[n] <= 64 ? dd[n] : 64;
                for (int c = 3; c * 8 < dcap; ++c) {
                    const int e = c * 8 + slot;
                    const int s = __shfl(idxv[n], e < 64 ? e : 0);
                    if (e < dcap) {
                        uint4 rr = yrows[(size_t)s * 8 + h];
                        a0 += blo(rr.x); a1 += bhi(rr.x);
                        a2 += blo(rr.y); a3 += bhi(rr.y);
                        a4 += blo(rr.z); a5 += bhi(rr.z);
                        a6 += blo(rr.w); a7 += bhi(rr.w);
                    }
                }
                if (dd[n] > 64) {
                    for (int jj = bg[n] + 64; jj < bg[n] + dd[n]; ++jj) {
                        const int s = csr[jj];
                        if (slot == 0) {
                            uint4 rr = yrows[(size_t)s * 8 + h];
                            a0 += blo(rr.x); a1 += bhi(rr.x);
                            a2 += blo(rr.y); a3 += bhi(rr.y);
                            a4 += blo(rr.z); a5 += bhi(rr.z);
                            a6 += blo(rr.w); a7 += bhi(rr.w);
                        }
                    }
                }
            }
            #pragma unroll
            for (int m = 8; m <= 32; m <<= 1) {
                a0 += __shfl_xor(a0, m); a1 += __shfl_xor(a1, m);
                a2 += __shfl_xor(a2, m); a3 += __shfl_xor(a3, m);
                a4 += __shfl_xor(a4, m); a5 += __shfl_xor(a5, m);
                a6 += __shfl_xor(a6, m); a7 += __shfl_xor(a7, m);
            }
            if (lane < 8) {
                *(float4*)&vbuf[wave][n][lane * 8]     = make_float4(a0, a1, a2, a3);
                *(float4*)&vbuf[wave][n][lane * 8 + 4] = make_float4(a4, a5, a6, a7);
            }
            vbuf[wave][n][lane] += selfv[n];
        }

        float a0 = bias, a1 = bias, a2 = bias, a3 = bias;
        #pragma unroll
        for (int k = 0; k < DIM; k += 4) {
            float4 q0 = *(const float4*)&vbuf[wave][0][k];
            float4 q1 = *(const float4*)&vbuf[wave][1][k];
            float4 q2 = *(const float4*)&vbuf[wave][2][k];
            float4 q3 = *(const float4*)&vbuf[wave][3][k];
            float w0 = W1s[(k + 0) * DIM + lane];
            float w1 = W1s[(k + 1) * DIM + lane];
            float w2 = W1s[(k + 2) * DIM + lane];
            float w3 = W1s[(k + 3) * DIM + lane];
            a0 = fmaf(q0.x, w0, a0); a0 = fmaf(q0.y, w1, a0);
            a0 = fmaf(q0.z, w2, a0); a0 = fmaf(q0.w, w3, a0);
            a1 = fmaf(q1.x, w0, a1); a1 = fmaf(q1.y, w1, a1);
            a1 = fmaf(q1.z, w2, a1); a1 = fmaf(q1.w, w3, a1);
            a2 = fmaf(q2.x, w0, a2); a2 = fmaf(q2.y, w1, a2);
            a2 = fmaf(q2.z, w2, a2); a2 = fmaf(q2.w, w3, a2);
            a3 = fmaf(q3.x, w0, a3); a3 = fmaf(q3.y, w1, a3);
            a3 = fmaf(q3.z, w2, a3); a3 = fmaf(q3.w, w3, a3);
        }

        const float wt0 = weights[i0 + 0];
        const float wt1 = weights[i0 + 1];
        const float wt2 = weights[i0 + 2];
        const float wt3 = weights[i0 + 3];
        sacc = fmaf(fmaxf(a0, 0.f), wt0, sacc);
        sacc = fmaf(fmaxf(a1, 0.f), wt1, sacc);
        sacc = fmaf(fmaxf(a2, 0.f), wt2, sacc);
        sacc = fmaf(fmaxf(a3, 0.f), wt3, sacc);
        if (lane == 0) swacc += wt0 + wt1 + wt2 + wt3;
    }

    sred[wave][lane] = sacc;
    __syncthreads();
    if (wave == 0) {
        float t = sred[0][lane] + sred[1][lane] + sred[2][lane] + sred[3][lane];
        atomicAdd(&sout[lane], t);
    }
    if (lane == 0) atomicAdd(&sout[DIM], swacc);
}

__global__ void finalize_kernel(
    const float* __restrict__ sout,
    const float* __restrict__ W2,
    const float* __restrict__ b2,
    float* __restrict__ out)
{
    const int j = threadIdx.x;
    const float sw = sout[DIM];
    float acc = sw * b2[j];
    #pragma unroll
    for (int k = 0; k < DIM; ++k)
        acc = fmaf(sout[k], W2[k * DIM + j], acc);
    out[j] = acc;
}

extern "C" void kernel_launch(void* const* d_in, const int* in_sizes, int n_in,
                              void* d_out, int out_size, void* d_ws, size_t ws_size,
                              hipStream_t stream)
{
    const float* x       = (const float*)d_in[0];
    int*         ebuf    = (int*)d_in[1];     // writable: harness restores before every launch
    const float* weights = (const float*)d_in[2];
    const float* W1      = (const float*)d_in[3];
    const float* b1      = (const float*)d_in[4];
    const float* W2      = (const float*)d_in[5];
    const float* b2      = (const float*)d_in[6];
    float* out = (float*)d_out;

    int* wsI = (int*)d_ws;

    int maxb = 0;
    hipError_t oe = hipOccupancyMaxActiveBlocksPerMultiprocessor(
        &maxb, (const void*)mega_kernel, 256, 0);
    bool coop_ok = (oe == hipSuccess) && (maxb >= 4);

    if (coop_ok) {
        void* args[] = {
            (void*)&x, (void*)&ebuf, (void*)&weights,
            (void*)&W1, (void*)&b1, (void*)&W2, (void*)&b2,
            (void*)&wsI, (void*)&out
        };
        hipLaunchCooperativeKernel((const void*)mega_kernel,
                                   dim3(NBLK), dim3(256), args, 0, stream);
    } else {
        const int* src = ebuf;
        const int* dst = ebuf + N_EDGES;
        int*      counts8 = wsI + OFF_COUNTS8;
        float*    soutF   = (float*)(wsI + OFF_SOUT);
        int*      tot     = wsI + OFF_TOT;
        int*      offsets = wsI + OFF_OFFSETS;
        int*      bsums   = wsI + OFF_BSUMS;
        int*      csr     = wsI + OFF_CSR;
        unsigned* rank8   = (unsigned*)(wsI + OFF_RANK8);
        unsigned* y16     = (unsigned*)(wsI + OFF_Y16);

        hipMemsetAsync(d_ws, 0, (size_t)(OFF_SOUT + 80) * sizeof(int), stream);
        convert_hist_kernel   <<<(ND4 + 255) / 256, 256, 0, stream>>>(x, y16, dst, counts8, rank8);
        colsum_blocksum_kernel<<<NB1,    256, 0, stream>>>(counts8, tot, bsums);
        offsets_kernel        <<<NB1,    256, 0, stream>>>(tot, bsums, offsets, counts8);
        fill_kernel           <<<E4BLK,  256, 0, stream>>>(src, dst, counts8, rank8, csr);
        gather_mlp_kernel     <<<NBLK_GM, 256, 0, stream>>>(x, y16, offsets, csr, weights, W1, b1, soutF);
        finalize_kernel       <<<1,       64, 0, stream>>>(soutF, W2, b2, out);
    }
}